// Round 5
// baseline (182.936 us; speedup 1.0000x reference)
//
#include <hip/hip_runtime.h>
#include <math.h>

#define NPTS 100000
#define NVERTS 6890
#define NJ 24

#define TPB 256
#define PPT 4                         // points per thread
#define PPB (TPB * PPT)               // 1024 points per block
#define NPB ((NPTS + PPB - 1) / PPB)  // 98 point-blocks
#define NCH 21                        // vertex chunks -> 98*21 = 2058 blocks (~8/CU)
#define STRIDE 329                    // ceil(NVERTS/NCH); chunk overlap is idempotent
#define ITER 336                      // STRIDE rounded up to multiple of 8
#define LDSN 344                      // ITER + 8 (prefetch overshoot), 5504 B LDS

// ---------------- Kernel 1: f32 NN scan, bit-matching the reference formula ----------------
// d2 = (xsq - 2*G) + vsq, G = ascending-k FMA dot (BLAS K=3), vsq = (vx^2+vy^2)+vz^2.
// Bit-exact vs numpy f32 -> argmin == np.argmin (strict <, first-index ties).
// Grid: x = point-block (98), y = vertex chunk (21). Partials merged via packed u64
// atomicMin (f32bits(d2)<<32)|idx: unsigned order == (d2, idx) lexicographic for d2>=0.
// Inner loop: two 4-vertex register banks, ping-pong; ds_read_b128 prefetch issued a
// full 4-vertex compute block (~260 cyc) ahead of its wait -> LDS latency hidden.
__global__ __launch_bounds__(256, 6) void nn_kernel(
    const float* __restrict__ xyz,
    const float* __restrict__ verts,
    unsigned long long* __restrict__ best_ws)
{
#pragma clang fp contract(off)
    __shared__ float4 vlds[LDSN];
    const int tid = threadIdx.x;
    const int vbase = blockIdx.y * STRIDE;

    for (int i = tid; i < LDSN; i += TPB) {
        const int v = vbase + i;
        if (v < NVERTS) {
            const float vx = verts[v * 3 + 0];
            const float vy = verts[v * 3 + 1];
            const float vz = verts[v * 3 + 2];
            vlds[i] = make_float4(vx, vy, vz, (vx * vx + vy * vy) + vz * vz);
        } else {
            vlds[i] = make_float4(0.0f, 0.0f, 0.0f, 1e30f);  // never wins
        }
    }
    __syncthreads();

    const int p0 = blockIdx.x * PPB + tid;
    float px0, py0, pz0, xs0, px1, py1, pz1, xs1;
    float px2, py2, pz2, xs2, px3, py3, pz3, xs3;
    float bs0 = 1e30f, bs1 = 1e30f, bs2 = 1e30f, bs3 = 1e30f;
    int bi0 = 0, bi1 = 0, bi2 = 0, bi3 = 0;

#define LOADPT(K) { \
    const int p = p0 + (K) * TPB; \
    const int pc = (p < NPTS) ? p : (NPTS - 1); \
    px##K = xyz[pc * 3 + 0]; py##K = xyz[pc * 3 + 1]; pz##K = xyz[pc * 3 + 2]; \
    xs##K = (px##K * px##K + py##K * py##K) + pz##K * pz##K; }
    LOADPT(0) LOADPT(1) LOADPT(2) LOADPT(3)
#undef LOADPT

#define STEP(V, VI) { \
    const int vi_ = (VI); \
    { float g = px0 * (V).x; g = fmaf(py0, (V).y, g); g = fmaf(pz0, (V).z, g); \
      const float d = fmaf(-2.0f, g, xs0) + (V).w; \
      bi0 = (d < bs0) ? vi_ : bi0; bs0 = fminf(bs0, d); } \
    { float g = px1 * (V).x; g = fmaf(py1, (V).y, g); g = fmaf(pz1, (V).z, g); \
      const float d = fmaf(-2.0f, g, xs1) + (V).w; \
      bi1 = (d < bs1) ? vi_ : bi1; bs1 = fminf(bs1, d); } \
    { float g = px2 * (V).x; g = fmaf(py2, (V).y, g); g = fmaf(pz2, (V).z, g); \
      const float d = fmaf(-2.0f, g, xs2) + (V).w; \
      bi2 = (d < bs2) ? vi_ : bi2; bs2 = fminf(bs2, d); } \
    { float g = px3 * (V).x; g = fmaf(py3, (V).y, g); g = fmaf(pz3, (V).z, g); \
      const float d = fmaf(-2.0f, g, xs3) + (V).w; \
      bi3 = (d < bs3) ? vi_ : bi3; bs3 = fminf(bs3, d); } }

    float4 a0 = vlds[0], a1 = vlds[1], a2 = vlds[2], a3 = vlds[3];
    #pragma unroll 1
    for (int i = 0; i + 8 <= ITER; i += 8) {
        // prefetch bank B (verts i+4..i+7) before computing bank A
        float4 b0 = vlds[i + 4], b1 = vlds[i + 5], b2 = vlds[i + 6], b3 = vlds[i + 7];
        STEP(a0, vbase + i + 0) STEP(a1, vbase + i + 1)
        STEP(a2, vbase + i + 2) STEP(a3, vbase + i + 3)
        // prefetch bank A (verts i+8..i+11; LDS padded to LDSN=344)
        a0 = vlds[i + 8]; a1 = vlds[i + 9]; a2 = vlds[i + 10]; a3 = vlds[i + 11];
        STEP(b0, vbase + i + 4) STEP(b1, vbase + i + 5)
        STEP(b2, vbase + i + 6) STEP(b3, vbase + i + 7)
    }
#undef STEP

#define FLUSH(K) { \
    const int p = p0 + (K) * TPB; \
    if (p < NPTS) { \
        const unsigned long long pk = \
            ((unsigned long long)__float_as_uint(bs##K) << 32) | (unsigned int)bi##K; \
        atomicMin(&best_ws[p], pk); \
    } }
    FLUSH(0) FLUSH(1) FLUSH(2) FLUSH(3)
#undef FLUSH
}

// ---------------- Kernel 2: per-point skinning + quaternion + outputs ----------------
__global__ __launch_bounds__(256) void apply_kernel(
    const float* __restrict__ xyz,
    const float* __restrict__ rot,
    const float* __restrict__ sw,
    const float* __restrict__ tm,
    const unsigned long long* __restrict__ best_ws,
    float* __restrict__ out)
{
    __shared__ float tl[NJ * 16];
    const int tid = threadIdx.x;
    for (int i = tid; i < NJ * 16; i += 256) tl[i] = tm[i];
    __syncthreads();

    const int p = blockIdx.x * 256 + tid;
    if (p >= NPTS) return;

    const int vi = (int)(best_ws[p] & 0xFFFFFFFFull);
    const float4* w4 = reinterpret_cast<const float4*>(sw + (size_t)vi * NJ);

    float T[16];
    #pragma unroll
    for (int i = 0; i < 16; ++i) T[i] = 0.0f;

    #pragma unroll
    for (int jq = 0; jq < NJ / 4; ++jq) {
        const float4 wv = w4[jq];
        const float wj[4] = { wv.x, wv.y, wv.z, wv.w };
        #pragma unroll
        for (int k = 0; k < 4; ++k) {
            const int j = jq * 4 + k;
            #pragma unroll
            for (int i = 0; i < 16; ++i)
                T[i] = fmaf(wj[k], tl[j * 16 + i], T[i]);
        }
    }

    // quaternion -> rotation matrix
    const float4 q = reinterpret_cast<const float4*>(rot)[p];
    float qr = q.x, qx = q.y, qy = q.z, qz = q.w;
    const float inv = 1.0f / sqrtf(qr * qr + qx * qx + qy * qy + qz * qz);
    qr *= inv; qx *= inv; qy *= inv; qz *= inv;
    float R[9];
    R[0] = 1.0f - 2.0f * (qy * qy + qz * qz);
    R[1] = 2.0f * (qx * qy - qr * qz);
    R[2] = 2.0f * (qx * qz + qr * qy);
    R[3] = 2.0f * (qx * qy + qr * qz);
    R[4] = 1.0f - 2.0f * (qx * qx + qz * qz);
    R[5] = 2.0f * (qy * qz - qr * qx);
    R[6] = 2.0f * (qx * qz - qr * qy);
    R[7] = 2.0f * (qy * qz + qr * qx);
    R[8] = 1.0f - 2.0f * (qx * qx + qy * qy);

    const float x0 = xyz[p * 3 + 0];
    const float x1 = xyz[p * 3 + 1];
    const float x2 = xyz[p * 3 + 2];

    // x_bar: out[0 .. 300000)
    #pragma unroll
    for (int i = 0; i < 3; ++i) {
        out[p * 3 + i] = fmaf(T[i * 4 + 0], x0,
                          fmaf(T[i * 4 + 1], x1,
                           fmaf(T[i * 4 + 2], x2, T[i * 4 + 3])));
    }

    // rotation_bar: out[300000 .. 1200000), [p][i][k] = sum_j T[i*4+j]*R[j*3+k]
    float* rb = out + 300000 + (size_t)p * 9;
    #pragma unroll
    for (int i = 0; i < 3; ++i) {
        #pragma unroll
        for (int k = 0; k < 3; ++k) {
            rb[i * 3 + k] = fmaf(T[i * 4 + 0], R[0 * 3 + k],
                             fmaf(T[i * 4 + 1], R[1 * 3 + k],
                                  T[i * 4 + 2] * R[2 * 3 + k]));
        }
    }

    // T_fwd: out[1200000 .. 2800000)
    float* tb = out + 1200000 + (size_t)p * 16;
    #pragma unroll
    for (int i = 0; i < 16; ++i) tb[i] = T[i];
}

extern "C" void kernel_launch(void* const* d_in, const int* in_sizes, int n_in,
                              void* d_out, int out_size, void* d_ws, size_t ws_size,
                              hipStream_t stream) {
    const float* xyz   = (const float*)d_in[0];
    const float* rot   = (const float*)d_in[1];
    const float* verts = (const float*)d_in[2];
    const float* sw    = (const float*)d_in[3];
    const float* tm    = (const float*)d_in[4];
    float* out = (float*)d_out;

    unsigned long long* best_ws = (unsigned long long*)d_ws;  // NPTS packed (d2,idx)

    // init packed mins to 0xFFFF... (max u64) each call -- capture-safe async memset
    hipMemsetAsync(d_ws, 0xFF, NPTS * sizeof(unsigned long long), stream);

    dim3 grid(NPB, NCH);  // 98 x 21 = 2058 blocks
    nn_kernel<<<grid, TPB, 0, stream>>>(xyz, verts, best_ws);
    apply_kernel<<<(NPTS + 255) / 256, 256, 0, stream>>>(xyz, rot, sw, tm, best_ws, out);
}

// Round 6
// 148.419 us; speedup vs baseline: 1.2326x; 1.2326x over previous
//
#include <hip/hip_runtime.h>
#include <math.h>

#define NPTS 100000
#define NVERTS 6890
#define NJ 24

#define TPB 256
#define PPT 4                           // points per thread
#define PPB (TPB * PPT)                 // 1024 points per block
#define NPB ((NPTS + PPB - 1) / PPB)    // 98 point-blocks
#define NCH 16                          // vertex chunks
#define VCH ((NVERTS + NCH - 1) / NCH)  // 431 verts/chunk
#define VCH2 ((VCH + 1) / 2)            // 216 vertex PAIRS/chunk; LDS 2*216*16 = 6912 B

typedef float f32x2 __attribute__((ext_vector_type(2)));
union PK { float4 f4; f32x2 h[2]; };

// ---------------- Kernel 1: f32 NN scan, packed-f32, bit-matching the reference ----------------
// d2 = (xsq - 2*G) + vsq, G = ascending-k FMA dot (BLAS K=3), vsq = (vx^2+vy^2)+vz^2.
// v_pk_{mul,fma,add}_f32 process 2 vertices/instr; each half is IEEE RTNE == scalar chain,
// so argmin still bit-matches np.argmin (strict <, vert0 before vert1 keeps first-index ties).
// LDS transposed-pair layout: A[j]={vx0,vx1,vy0,vy1}, B[j]={vz0,vz1,vsq0,vsq1} -> packed
// operands land as even-aligned VGPR subpairs of two ds_read_b128 (no shuffles).
// Partials merged via packed u64 atomicMin (f32bits(d2)<<32)|idx (lexicographic for d2>=0);
// cross-chunk duplicate pairs are idempotent, OOB slots sentinel vsq=1e30.
__global__ __launch_bounds__(256, 4) void nn_kernel(
    const float* __restrict__ xyz,
    const float* __restrict__ verts,
    unsigned long long* __restrict__ best_ws)
{
#pragma clang fp contract(off)
    __shared__ float4 vldsA[VCH2];
    __shared__ float4 vldsB[VCH2];
    const int tid = threadIdx.x;
    const int vbase = blockIdx.y * VCH;

    for (int j = tid; j < VCH2; j += TPB) {
        const int v0 = vbase + 2 * j;
        const int v1 = v0 + 1;
        float x0 = 0.f, y0 = 0.f, z0 = 0.f, q0 = 1e30f;
        float x1 = 0.f, y1 = 0.f, z1 = 0.f, q1 = 1e30f;
        if (v0 < NVERTS) {
            x0 = verts[v0 * 3 + 0]; y0 = verts[v0 * 3 + 1]; z0 = verts[v0 * 3 + 2];
            q0 = (x0 * x0 + y0 * y0) + z0 * z0;
        }
        if (v1 < NVERTS) {
            x1 = verts[v1 * 3 + 0]; y1 = verts[v1 * 3 + 1]; z1 = verts[v1 * 3 + 2];
            q1 = (x1 * x1 + y1 * y1) + z1 * z1;
        }
        vldsA[j] = make_float4(x0, x1, y0, y1);
        vldsB[j] = make_float4(z0, z1, q0, q1);
    }
    __syncthreads();

    const int p0 = blockIdx.x * PPB + tid;
    f32x2 px2[PPT], py2[PPT], pz2[PPT], xs2[PPT];
    float bs[PPT];
    int bi[PPT];
    #pragma unroll
    for (int k = 0; k < PPT; ++k) {
        const int p = p0 + k * TPB;
        const int pc = (p < NPTS) ? p : (NPTS - 1);
        const float x = xyz[pc * 3 + 0];
        const float y = xyz[pc * 3 + 1];
        const float z = xyz[pc * 3 + 2];
        const float xs = (x * x + y * y) + z * z;
        px2[k] = (f32x2){x, x};  py2[k] = (f32x2){y, y};
        pz2[k] = (f32x2){z, z};  xs2[k] = (f32x2){xs, xs};
        bs[k] = 1e30f;
        bi[k] = 0;
    }
    const f32x2 m2 = {-2.0f, -2.0f};

    #pragma unroll 2
    for (int j = 0; j < VCH2; ++j) {
        PK A, B;
        A.f4 = vldsA[j];   // uniform-address broadcast ds_read_b128
        B.f4 = vldsB[j];
        const f32x2 vx2 = A.h[0], vy2 = A.h[1];
        const f32x2 vz2 = B.h[0], vq2 = B.h[1];
        const int vi0 = vbase + 2 * j;
        #pragma unroll
        for (int k = 0; k < PPT; ++k) {
            f32x2 g = px2[k] * vx2;                        // v_pk_mul_f32: rnd(x0*vx)
            g = __builtin_elementwise_fma(py2[k], vy2, g); // v_pk_fma_f32 (ascending k)
            g = __builtin_elementwise_fma(pz2[k], vz2, g);
            f32x2 d = __builtin_elementwise_fma(m2, g, xs2[k]);  // rnd(xsq-2G), 2G exact
            d = d + vq2;                                   // v_pk_add_f32: rnd(t+vsq)
            // vert0 then vert1: preserves ascending-index, first-index-tie argmin
            bi[k] = (d.x < bs[k]) ? vi0 : bi[k];
            bs[k] = fminf(bs[k], d.x);
            bi[k] = (d.y < bs[k]) ? (vi0 + 1) : bi[k];
            bs[k] = fminf(bs[k], d.y);
        }
    }

    #pragma unroll
    for (int k = 0; k < PPT; ++k) {
        const int p = p0 + k * TPB;
        if (p < NPTS) {
            const unsigned long long pk =
                ((unsigned long long)__float_as_uint(bs[k]) << 32) |
                (unsigned int)bi[k];
            atomicMin(&best_ws[p], pk);
        }
    }
}

// ---------------- Kernel 2: per-point skinning + quaternion + outputs ----------------
__global__ __launch_bounds__(256) void apply_kernel(
    const float* __restrict__ xyz,
    const float* __restrict__ rot,
    const float* __restrict__ sw,
    const float* __restrict__ tm,
    const unsigned long long* __restrict__ best_ws,
    float* __restrict__ out)
{
    __shared__ float tl[NJ * 16];
    const int tid = threadIdx.x;
    for (int i = tid; i < NJ * 16; i += 256) tl[i] = tm[i];
    __syncthreads();

    const int p = blockIdx.x * 256 + tid;
    if (p >= NPTS) return;

    const int vi = (int)(best_ws[p] & 0xFFFFFFFFull);
    const float4* w4 = reinterpret_cast<const float4*>(sw + (size_t)vi * NJ);

    float T[16];
    #pragma unroll
    for (int i = 0; i < 16; ++i) T[i] = 0.0f;

    #pragma unroll
    for (int jq = 0; jq < NJ / 4; ++jq) {
        const float4 wv = w4[jq];
        const float wj[4] = { wv.x, wv.y, wv.z, wv.w };
        #pragma unroll
        for (int k = 0; k < 4; ++k) {
            const int j = jq * 4 + k;
            #pragma unroll
            for (int i = 0; i < 16; ++i)
                T[i] = fmaf(wj[k], tl[j * 16 + i], T[i]);
        }
    }

    // quaternion -> rotation matrix
    const float4 q = reinterpret_cast<const float4*>(rot)[p];
    float qr = q.x, qx = q.y, qy = q.z, qz = q.w;
    const float inv = 1.0f / sqrtf(qr * qr + qx * qx + qy * qy + qz * qz);
    qr *= inv; qx *= inv; qy *= inv; qz *= inv;
    float R[9];
    R[0] = 1.0f - 2.0f * (qy * qy + qz * qz);
    R[1] = 2.0f * (qx * qy - qr * qz);
    R[2] = 2.0f * (qx * qz + qr * qy);
    R[3] = 2.0f * (qx * qy + qr * qz);
    R[4] = 1.0f - 2.0f * (qx * qx + qz * qz);
    R[5] = 2.0f * (qy * qz - qr * qx);
    R[6] = 2.0f * (qx * qz - qr * qy);
    R[7] = 2.0f * (qy * qz + qr * qx);
    R[8] = 1.0f - 2.0f * (qx * qx + qy * qy);

    const float x0 = xyz[p * 3 + 0];
    const float x1 = xyz[p * 3 + 1];
    const float x2 = xyz[p * 3 + 2];

    // x_bar: out[0 .. 300000)
    #pragma unroll
    for (int i = 0; i < 3; ++i) {
        out[p * 3 + i] = fmaf(T[i * 4 + 0], x0,
                          fmaf(T[i * 4 + 1], x1,
                           fmaf(T[i * 4 + 2], x2, T[i * 4 + 3])));
    }

    // rotation_bar: out[300000 .. 1200000), [p][i][k] = sum_j T[i*4+j]*R[j*3+k]
    float* rb = out + 300000 + (size_t)p * 9;
    #pragma unroll
    for (int i = 0; i < 3; ++i) {
        #pragma unroll
        for (int k = 0; k < 3; ++k) {
            rb[i * 3 + k] = fmaf(T[i * 4 + 0], R[0 * 3 + k],
                             fmaf(T[i * 4 + 1], R[1 * 3 + k],
                                  T[i * 4 + 2] * R[2 * 3 + k]));
        }
    }

    // T_fwd: out[1200000 .. 2800000)
    float* tb = out + 1200000 + (size_t)p * 16;
    #pragma unroll
    for (int i = 0; i < 16; ++i) tb[i] = T[i];
}

extern "C" void kernel_launch(void* const* d_in, const int* in_sizes, int n_in,
                              void* d_out, int out_size, void* d_ws, size_t ws_size,
                              hipStream_t stream) {
    const float* xyz   = (const float*)d_in[0];
    const float* rot   = (const float*)d_in[1];
    const float* verts = (const float*)d_in[2];
    const float* sw    = (const float*)d_in[3];
    const float* tm    = (const float*)d_in[4];
    float* out = (float*)d_out;

    unsigned long long* best_ws = (unsigned long long*)d_ws;  // NPTS packed (d2,idx)

    // init packed mins to 0xFFFF... (max u64) each call -- capture-safe async memset
    hipMemsetAsync(d_ws, 0xFF, NPTS * sizeof(unsigned long long), stream);

    dim3 grid(NPB, NCH);  // 98 x 16 = 1568 blocks
    nn_kernel<<<grid, TPB, 0, stream>>>(xyz, verts, best_ws);
    apply_kernel<<<(NPTS + 255) / 256, 256, 0, stream>>>(xyz, rot, sw, tm, best_ws, out);
}